// Round 5
// baseline (360.826 us; speedup 1.0000x reference)
//
#include <hip/hip_runtime.h>

#define NN 4096
#define DD 256
#define EE 131072

typedef __attribute__((ext_vector_type(8))) short s16x8;
typedef __attribute__((ext_vector_type(4))) float f32x4;

__device__ __forceinline__ unsigned short f2bf(float f) {
  unsigned u = __builtin_bit_cast(unsigned, f);
  u += 0x7FFFu + ((u >> 16) & 1u);
  return (unsigned short)(u >> 16);
}

__device__ __forceinline__ ushort4 cvt4(f32x4 v) {
  ushort4 r;
  r.x = f2bf(v[0]); r.y = f2bf(v[1]); r.z = f2bf(v[2]); r.w = f2bf(v[3]);
  return r;
}

// round-half-up fp32->bf16 pair pack
__device__ __forceinline__ unsigned cvt2_rhu(float a, float b) {
  unsigned ua = __builtin_bit_cast(unsigned, a) + 0x8000u;
  unsigned ub = __builtin_bit_cast(unsigned, b) + 0x8000u;
  return __builtin_amdgcn_perm(ub, ua, 0x07060302u);
}

__device__ __forceinline__ s16x8 frag_from(f32x4 a, f32x4 b) {
  uint4 u;
  u.x = cvt2_rhu(a[0], a[1]); u.y = cvt2_rhu(a[2], a[3]);
  u.z = cvt2_rhu(b[0], b[1]); u.w = cvt2_rhu(b[2], b[3]);
  return __builtin_bit_cast(s16x8, u);
}

// Fragment layout (identical for A- and B-operands of mfma_16x16x32_bf16):
//   matrix element (r, k)  [r = m-row for A / n-col for B] lives at
//   chunk = (rtile * NKCHUNK + kchunk), intra-chunk ushort index
//   ((k>>3)&3)*128 + (r&15)*8 + (k&7);  chunk = 512 elements = one wave-load
//   of 1 KB at  base + chunk*512 + lane*8.

// ---------------------------------------------------------------------------
// K1: count in-degrees + write both W matrices in B-fragment layout (bf16)
// ---------------------------------------------------------------------------
__global__ void k_prep(const int* __restrict__ ei, int* __restrict__ deg,
                       const float* __restrict__ Wh, const float* __restrict__ Wc,
                       unsigned short* __restrict__ WFh, unsigned short* __restrict__ WFc) {
  int t = blockIdx.x * 256 + threadIdx.x;
  if (t < EE) {
    atomicAdd(&deg[ei[EE + t]], 1);
  } else {
    int idx = t - EE;
    int which = idx >> 16;
    int r = idx & 65535;
    int n = r & 255, k = r >> 8;
    const float* W = which ? Wc : Wh;
    unsigned short* WF = which ? WFc : WFh;
    long fidx = ((long)((n >> 4) * 8 + (k >> 5))) * 512 +
                (((k >> 3) & 3) * 128 + (n & 15) * 8 + (k & 7));
    WF[fidx] = f2bf(W[k * 256 + n]);
  }
}

// ---------------------------------------------------------------------------
// K2: dis[i] = rsqrt(deg[i]+1); add diagonal dis^2 into M (fp32 frag layout)
// ---------------------------------------------------------------------------
__global__ void k_dis(const int* __restrict__ deg, float* __restrict__ dis,
                      float* __restrict__ M) {
  int i = blockIdx.x * 256 + threadIdx.x;
  float d = rsqrtf((float)deg[i] + 1.0f);
  dis[i] = d;
  long idx = ((long)((i >> 4) * 128 + (i >> 5))) * 512 +
             (((i >> 3) & 3) * 128 + (i & 15) * 8 + (i & 7));
  atomicAdd(&M[idx], d * d);
}

// ---------------------------------------------------------------------------
// K3: scatter edges into dense normalized adjacency M (fp32, A-frag layout)
//     M[dst][src] += dis[dst]*dis[src]
// ---------------------------------------------------------------------------
__global__ void k_scatterM(const int* __restrict__ ei, const float* __restrict__ dis,
                           float* __restrict__ M) {
  int e = blockIdx.x * 256 + threadIdx.x;
  if (e < EE) {
    int s = ei[e];
    int d = ei[EE + e];
    float v = dis[d] * dis[s];
    long idx = ((long)((d >> 4) * 128 + (s >> 5))) * 512 +
               (((s >> 3) & 3) * 128 + (d & 15) * 8 + (s & 7));
    atomicAdd(&M[idx], v);
  }
}

// ---------------------------------------------------------------------------
// K4: RF = frag(relu(x @ W_high)),  XWcF = frag(x @ W_conv)
//     grid 256 (16-row M-tiles), block 512. waves 0-3: high, 4-7: conv.
// ---------------------------------------------------------------------------
__global__ __launch_bounds__(512) void k_xw(const float* __restrict__ x,
                                            const unsigned short* __restrict__ WFh,
                                            const unsigned short* __restrict__ WFc,
                                            unsigned short* __restrict__ RF,
                                            unsigned short* __restrict__ XWcF) {
  __shared__ alignas(16) unsigned short Abuf[16][264];
  const int tid = threadIdx.x;
  const int w = tid >> 6, lane = tid & 63;
  const int quad = lane >> 4, l16 = lane & 15, quad8 = quad * 8;
  const int m0 = blockIdx.x * 16;

  {
    int srow = tid >> 5, scolf = (tid & 31) * 8;
    const float* ap = x + (long)(m0 + srow) * DD + scolf;
    f32x4 a0 = *(const f32x4*)ap;
    f32x4 a1 = *(const f32x4*)(ap + 4);
    uint4 u;
    u.x = cvt2_rhu(a0[0], a0[1]); u.y = cvt2_rhu(a0[2], a0[3]);
    u.z = cvt2_rhu(a1[0], a1[1]); u.w = cvt2_rhu(a1[2], a1[3]);
    *(uint4*)&Abuf[srow][scolf] = u;
  }
  __syncthreads();

  const bool hi = (w < 4);
  const int wo = hi ? w : (w - 4);
  const unsigned short* WF = hi ? WFh : WFc;
  unsigned short* OUT = hi ? RF : XWcF;
  const unsigned short* bp = WF + lane * 8;

  f32x4 acc[4] = {{0,0,0,0},{0,0,0,0},{0,0,0,0},{0,0,0,0}};
#pragma unroll
  for (int q = 0; q < 8; ++q) {
    s16x8 af = *(const s16x8*)&Abuf[l16][q * 32 + quad8];
#pragma unroll
    for (int s = 0; s < 4; ++s) {
      s16x8 bf = *(const s16x8*)(bp + ((long)((4 * wo + s) * 8 + q)) * 512);
      acc[s] = __builtin_amdgcn_mfma_f32_16x16x32_bf16(af, bf, acc[s], 0, 0, 0);
    }
  }

  // store as B-frag(n = col, k = row m): chunk(ntile = 4*wo+s, kchunk = m0>>5)
  const int kc = m0 >> 5;
  const int qp = ((m0 >> 4) & 1) * 2 + (quad >> 1);
  const int j0 = (quad & 1) * 4;
#pragma unroll
  for (int s = 0; s < 4; ++s) {
    int t = 4 * wo + s;
    f32x4 v = acc[s];
    if (hi) {
      v[0] = v[0] > 0.f ? v[0] : 0.f;
      v[1] = v[1] > 0.f ? v[1] : 0.f;
      v[2] = v[2] > 0.f ? v[2] : 0.f;
      v[3] = v[3] > 0.f ? v[3] : 0.f;
    }
    long idx = ((long)(t * 128 + kc)) * 512 + (qp * 16 + l16) * 8 + j0;
    *(ushort4*)(OUT + idx) = cvt4(v);
  }
}

// ---------------------------------------------------------------------------
// K5: split-K fragment GEMM, barrier-free, no LDS.
//   C[4096x256] = A @ B.  grid 256 = ks*32 + mgrp (8 k-splits x 32 m-groups).
//   Block 512 = 8 waves; wave = (mh = w&1) 64 rows x (nq = w>>2... w>>1) 64 cols,
//   acc[4][4]. Per kchunk (32 k): 4 A-frags + 4 B-frags (1 KB coalesced each),
//   16 MFMA. Depth-1 register prefetch; waves self-pipeline via vmcnt.
//   AMODE 0: A = bf16 frags. 1: A = fp32 row-major (inline convert).
//            2: A = fp32 in frag layout (inline convert).
//   EMIT: write converted A-frags to AFout (waves with nq==0 only).
//   Output: fp32 partials P[ks][4096][256].
// ---------------------------------------------------------------------------
template <int AMODE, int EMIT>
__global__ __launch_bounds__(512) void k_gemm(const float* __restrict__ Afp,
                                              const unsigned short* __restrict__ AFin,
                                              const unsigned short* __restrict__ BF,
                                              float* __restrict__ P,
                                              unsigned short* __restrict__ AFout) {
  const int tid = threadIdx.x;
  const int w = tid >> 6, lane = tid & 63;
  const int quad = lane >> 4, l16 = lane & 15;
  const int mgrp = blockIdx.x & 31, ks = blockIdx.x >> 5;
  const int m0 = mgrp * 128;
  const int mh = w & 1, nq = w >> 1;
  const int kc0 = ks * 16;

  const long mtile0 = (long)(mgrp * 8 + mh * 4);
  const unsigned short* bptr = BF + (((long)(nq * 4) * 128 + kc0) << 9) + lane * 8;
  const unsigned short* aptrF = AFin + ((mtile0 * 128 + kc0) << 9) + lane * 8;
  const float* aptrR = Afp + (long)(m0 + mh * 64 + l16) * NN + kc0 * 32 + quad * 8;
  const float* aptr2 = Afp + ((mtile0 * 128 + kc0) << 9) + lane * 8;
  unsigned short* aout = AFout + ((mtile0 * 128 + kc0) << 9) + lane * 8;

  f32x4 acc[4][4];
#pragma unroll
  for (int mi = 0; mi < 4; ++mi)
#pragma unroll
    for (int ti = 0; ti < 4; ++ti) acc[mi][ti] = (f32x4){0, 0, 0, 0};

  s16x8 bfr[2][4];
  s16x8 afr[2][4];
  f32x4 arw[2][8];

#define LOADB(buf, kcv)                                                         \
  _Pragma("unroll") for (int ti = 0; ti < 4; ++ti)                              \
      bfr[buf][ti] = *(const s16x8*)(bptr + (((long)(ti * 128 + (kcv))) << 9));

#define LOADA(buf, kcv)                                                         \
  if (AMODE == 0) {                                                             \
    _Pragma("unroll") for (int mi = 0; mi < 4; ++mi)                            \
        afr[buf][mi] = *(const s16x8*)(aptrF + (((long)(mi * 128 + (kcv))) << 9)); \
  } else if (AMODE == 1) {                                                      \
    _Pragma("unroll") for (int mi = 0; mi < 4; ++mi) {                          \
      arw[buf][2 * mi] = *(const f32x4*)(aptrR + (long)mi * 16 * NN + (kcv) * 32); \
      arw[buf][2 * mi + 1] = *(const f32x4*)(aptrR + (long)mi * 16 * NN + (kcv) * 32 + 4); \
    }                                                                           \
  } else {                                                                      \
    _Pragma("unroll") for (int mi = 0; mi < 4; ++mi) {                          \
      arw[buf][2 * mi] = *(const f32x4*)(aptr2 + (((long)(mi * 128 + (kcv))) << 9)); \
      arw[buf][2 * mi + 1] = *(const f32x4*)(aptr2 + (((long)(mi * 128 + (kcv))) << 9) + 4); \
    }                                                                           \
  }

  LOADB(0, 0)
  LOADA(0, 0)

#pragma unroll
  for (int kc = 0; kc < 16; ++kc) {
    const int cur = kc & 1, nxt = cur ^ 1;
    if (kc < 15) {
      LOADB(nxt, kc + 1)
      LOADA(nxt, kc + 1)
    }
    s16x8 A4[4];
    if (AMODE == 0) {
#pragma unroll
      for (int mi = 0; mi < 4; ++mi) A4[mi] = afr[cur][mi];
    } else {
#pragma unroll
      for (int mi = 0; mi < 4; ++mi)
        A4[mi] = frag_from(arw[cur][2 * mi], arw[cur][2 * mi + 1]);
    }
    if (EMIT) {
      if (nq == 0) {
#pragma unroll
        for (int mi = 0; mi < 4; ++mi)
          *(s16x8*)(aout + (((long)(mi * 128 + kc)) << 9)) = A4[mi];
      }
    }
#pragma unroll
    for (int ti = 0; ti < 4; ++ti)
#pragma unroll
      for (int mi = 0; mi < 4; ++mi)
        acc[mi][ti] = __builtin_amdgcn_mfma_f32_16x16x32_bf16(A4[mi], bfr[cur][ti], acc[mi][ti], 0, 0, 0);
  }
#undef LOADA
#undef LOADB

  float* pb = P + (long)ks * NN * DD;
#pragma unroll
  for (int mi = 0; mi < 4; ++mi) {
    const int row = m0 + mh * 64 + mi * 16 + quad * 4;
#pragma unroll
    for (int ti = 0; ti < 4; ++ti) {
      const int col = nq * 64 + ti * 16 + l16;
#pragma unroll
      for (int r = 0; r < 4; ++r)
        pb[(long)(row + r) * DD + col] = acc[mi][ti][r];
    }
  }
}

// ---------------------------------------------------------------------------
// K6: reduce 8 partials -> bf16 fragment output (B-frag of T[k][n])
//     grid 256 x 256; 4 waves/block, 2 chunks/wave -> 2048 chunks
// ---------------------------------------------------------------------------
__global__ void k_redF(const float* __restrict__ P, unsigned short* __restrict__ TF) {
  const int tid = threadIdx.x;
  const int w = tid >> 6, lane = tid & 63;
  const int quad = lane >> 4, l16 = lane & 15;
#pragma unroll
  for (int c = 0; c < 2; ++c) {
    int cid = blockIdx.x * 8 + w * 2 + c;
    int ntile = cid >> 7, kchunk = cid & 127;
    int n = ntile * 16 + l16;
    int kbase = kchunk * 32 + quad * 8;
    float v[8];
#pragma unroll
    for (int j = 0; j < 8; ++j) v[j] = 0.f;
#pragma unroll
    for (int s = 0; s < 8; ++s) {
      const float* p = P + (long)s * NN * DD;
#pragma unroll
      for (int j = 0; j < 8; ++j) v[j] += p[(long)(kbase + j) * DD + n];
    }
    ushort4 o0, o1;
    o0.x = f2bf(v[0]); o0.y = f2bf(v[1]); o0.z = f2bf(v[2]); o0.w = f2bf(v[3]);
    o1.x = f2bf(v[4]); o1.y = f2bf(v[5]); o1.z = f2bf(v[6]); o1.w = f2bf(v[7]);
    *(ushort4*)(TF + (long)cid * 512 + lane * 8) = o0;
    *(ushort4*)(TF + (long)cid * 512 + lane * 8 + 4) = o1;
  }
}

// ---------------------------------------------------------------------------
// K7: reduce 8 partials -> fp32 Hl
// ---------------------------------------------------------------------------
__global__ void k_redHl(const float* __restrict__ P, float* __restrict__ Hl) {
  long off = ((long)blockIdx.x * 256 + threadIdx.x) * 4;
  f32x4 v = {0, 0, 0, 0};
#pragma unroll
  for (int s = 0; s < 8; ++s) {
    f32x4 p = *(const f32x4*)(P + (long)s * NN * DD + off);
    v[0] += p[0]; v[1] += p[1]; v[2] += p[2]; v[3] += p[3];
  }
  *(f32x4*)(Hl + off) = v;
}

// ---------------------------------------------------------------------------
// K8: final: out = aH * sum(Ph) + aL * (Hl + b)
// ---------------------------------------------------------------------------
__global__ void k_final(const float* __restrict__ P, const float* __restrict__ Hl,
                        const float* __restrict__ bconv, const float* __restrict__ aLp,
                        const float* __restrict__ aHp, float* __restrict__ out) {
  long off = ((long)blockIdx.x * 256 + threadIdx.x) * 4;
  f32x4 v = {0, 0, 0, 0};
#pragma unroll
  for (int s = 0; s < 8; ++s) {
    f32x4 p = *(const f32x4*)(P + (long)s * NN * DD + off);
    v[0] += p[0]; v[1] += p[1]; v[2] += p[2]; v[3] += p[3];
  }
  const float aLv = aLp[0], aHv = aHp[0];
  f32x4 h = *(const f32x4*)(Hl + off);
  f32x4 b = *(const f32x4*)(bconv + (int)(off & 255));
  f32x4 res;
  res[0] = aHv * v[0] + aLv * (h[0] + b[0]);
  res[1] = aHv * v[1] + aLv * (h[1] + b[1]);
  res[2] = aHv * v[2] + aLv * (h[2] + b[2]);
  res[3] = aHv * v[3] + aLv * (h[3] + b[3]);
  *(f32x4*)(out + off) = res;
}

// ---------------------------------------------------------------------------
// launcher.  ws layout (MB):
//   [0,64)  M (fp32 frag)  -- after G4 done, [0,32) is reused as dinvF (bf16)
//   [64,96) P (fp32 partials, shared by all 4 GEMMs sequentially)
//   [96,..) WFh, WFc, RF, XWcF, T1F, T2F, Hl, deg, dis   (~13 MB)
// ---------------------------------------------------------------------------
extern "C" void kernel_launch(void* const* d_in, const int* in_sizes, int n_in,
                              void* d_out, int out_size, void* d_ws, size_t ws_size,
                              hipStream_t stream) {
  const float* x     = (const float*)d_in[0];
  const int*   ei    = (const int*)d_in[1];
  const float* lap   = (const float*)d_in[2];
  const float* dinv  = (const float*)d_in[3];
  const float* Wh    = (const float*)d_in[4];
  const float* Wc    = (const float*)d_in[5];
  const float* bconv = (const float*)d_in[6];
  const float* aL    = (const float*)d_in[7];
  const float* aH    = (const float*)d_in[8];
  float* out = (float*)d_out;
  char* ws = (char*)d_ws;
  const long MB = 1l << 20;

  float* M              = (float*)(ws);                 // 64 MB
  unsigned short* dinvF = (unsigned short*)(ws);        // 32 MB (after G4)
  float* P              = (float*)(ws + 64 * MB);       // 32 MB
  unsigned short* WFh   = (unsigned short*)(ws + 96 * MB);
  unsigned short* WFc   = (unsigned short*)(ws + 96 * MB + 128 * 1024);
  unsigned short* RF    = (unsigned short*)(ws + 97 * MB);   // 2 MB
  unsigned short* XWcF  = (unsigned short*)(ws + 99 * MB);   // 2 MB
  unsigned short* T1F   = (unsigned short*)(ws + 101 * MB);  // 2 MB
  unsigned short* T2F   = (unsigned short*)(ws + 103 * MB);  // 2 MB
  float* Hl             = (float*)(ws + 105 * MB);           // 4 MB
  int* deg              = (int*)(ws + 109 * MB);             // 16 KB
  float* dis            = (float*)(ws + 109 * MB + 16 * 1024);

  hipMemsetAsync(M, 0, 64 * MB, stream);
  hipMemsetAsync(deg, 0, 16 * 1024, stream);

  k_prep<<<1024, 256, 0, stream>>>(ei, deg, Wh, Wc, WFh, WFc);
  k_dis<<<16, 256, 0, stream>>>(deg, dis, M);
  k_scatterM<<<512, 256, 0, stream>>>(ei, dis, M);
  k_xw<<<256, 512, 0, stream>>>(x, WFh, WFc, RF, XWcF);

  // G4: Pl = M @ XWcF   (A fp32 in frag layout)
  k_gemm<2, 0><<<256, 512, 0, stream>>>(M, nullptr, XWcF, P, nullptr);
  k_redHl<<<1024, 256, 0, stream>>>(P, Hl);

  // G1: T1 = dinv @ R   (A fp32 row-major; emits dinvF)
  k_gemm<1, 1><<<256, 512, 0, stream>>>(dinv, nullptr, RF, P, dinvF);
  k_redF<<<256, 256, 0, stream>>>(P, T1F);

  // G2: T2 = lap @ T1   (A fp32 row-major)
  k_gemm<1, 0><<<256, 512, 0, stream>>>(lap, nullptr, T1F, P, nullptr);
  k_redF<<<256, 256, 0, stream>>>(P, T2F);

  // G3: Hh = dinv @ T2  (A bf16 frags from G1)
  k_gemm<0, 0><<<256, 512, 0, stream>>>(nullptr, dinvF, T2F, P, nullptr);

  k_final<<<1024, 256, 0, stream>>>(P, Hl, bconv, aL, aH, out);
}